// Round 1
// baseline (3743.386 us; speedup 1.0000x reference)
//
#include <hip/hip_runtime.h>

#define NPG 57       // nodes per graph
#define NEPG 160     // edges per graph (80 branches * 2)
#define NB 80        // branches per graph
#define HID 128
#define NG 4096      // graphs
#define NLAYERS 5
#define RMAX 29      // ceil(57/2) rows per thread-group

__global__ __launch_bounds__(256, 2) void pinn_fused(
    const float* __restrict__ x,          // [N,4]
    const int* __restrict__ edge_index,   // [2,E]
    const int* __restrict__ branch_u,     // [80]
    const int* __restrict__ branch_v,     // [80]
    const float* __restrict__ Wp,         // [4,128]
    const float* __restrict__ bp,         // [128]
    const float* __restrict__ convW,      // [5,128,128]
    const float* __restrict__ convb,      // [5,128]
    const float* __restrict__ bn_gamma,   // [5,128]
    const float* __restrict__ bn_beta,    // [5,128]
    const float* __restrict__ bn_mean,    // [5,128]
    const float* __restrict__ bn_var,     // [5,128]
    const float* __restrict__ physW1,     // [128,16]
    const float* __restrict__ physb1,     // [16]
    const float* __restrict__ physW2,     // [16,1]
    const float* __restrict__ physb2,     // [1]
    const float* __restrict__ mlpW1,      // [257,128]
    const float* __restrict__ mlpb1,      // [128]
    const float* __restrict__ mlpW2,      // [128,1]
    const float* __restrict__ mlpb2,      // [1]
    float* __restrict__ out)              // [NG*80]
{
    __shared__ float h[NPG][HID];    // 29184 B
    __shared__ float m[NPG][HID];    // 29184 B
    __shared__ float dinv[NPG];
    __shared__ float degf[NPG];
    __shared__ short esrc[NEPG];
    __shared__ short edst[NEPG];
    __shared__ float enorm[NEPG];
    __shared__ float theta[NPG];
    __shared__ float red[NB];

    const int g = blockIdx.x;
    const int tid = threadIdx.x;
    const int c = tid & (HID - 1);   // channel 0..127
    const int rg = tid >> 7;         // row group 0/1 (wave-uniform)

    // ---- init ----
    if (tid < NPG) degf[tid] = 1.0f;   // self-loop contributes 1 to degree
    if (tid < NB) red[tid] = 0.0f;
    __syncthreads();

    // ---- load edges (local indices), count in-degree ----
    const int E = NG * NEPG;
    for (int e = tid; e < NEPG; e += 256) {
        int gs = edge_index[g * NEPG + e];        // row 0: src (global id)
        int gd = edge_index[E + g * NEPG + e];    // row 1: dst (global id)
        short ls = (short)(gs - g * NPG);
        short ld = (short)(gd - g * NPG);
        esrc[e] = ls;
        edst[e] = ld;
        atomicAdd(&degf[ld], 1.0f);
    }
    __syncthreads();
    if (tid < NPG) dinv[tid] = rsqrtf(degf[tid]);
    __syncthreads();
    for (int e = tid; e < NEPG; e += 256)
        enorm[e] = dinv[esrc[e]] * dinv[edst[e]];

    // ---- projection: h = x @ Wp + bp ----
    {
        float w0 = Wp[c], w1 = Wp[HID + c], w2 = Wp[2 * HID + c], w3 = Wp[3 * HID + c];
        float bb = bp[c];
        const float4* x4 = (const float4*)x;
        #pragma unroll
        for (int ri = 0; ri < RMAX; ++ri) {
            int r = rg + 2 * ri;
            if (r < NPG) {
                float4 xv = x4[g * NPG + r];
                h[r][c] = fmaf(xv.x, w0, fmaf(xv.y, w1, fmaf(xv.z, w2, fmaf(xv.w, w3, bb))));
            }
        }
    }
    __syncthreads();

    // ---- 5 GCN layers ----
    for (int l = 0; l < NLAYERS; ++l) {
        // A: aggregate (norm-weighted) into m.  m = D^-1/2 A D^-1/2 h  (incl. self loop)
        #pragma unroll
        for (int ri = 0; ri < RMAX; ++ri) {
            int r = rg + 2 * ri;
            if (r < NPG) m[r][c] = dinv[r] * dinv[r] * h[r][c];
        }
        __syncthreads();
        for (int e = rg; e < NEPG; e += 2) {
            int s = esrc[e], d = edst[e];
            atomicAdd(&m[d][c], enorm[e] * h[s][c]);
        }
        __syncthreads();

        // B: (m @ W + b) -> BN -> ReLU -> += residual(h)
        const float* __restrict__ W = convW + l * HID * HID;
        float scale = bn_gamma[l * HID + c] * rsqrtf(bn_var[l * HID + c] + 1e-5f);
        float shift = bn_beta[l * HID + c] - bn_mean[l * HID + c] * scale;
        float bc = convb[l * HID + c];
        float acc[RMAX];
        #pragma unroll
        for (int ri = 0; ri < RMAX; ++ri) acc[ri] = 0.0f;
        for (int k = 0; k < HID; k += 4) {
            float w0 = W[(k + 0) * HID + c];
            float w1 = W[(k + 1) * HID + c];
            float w2 = W[(k + 2) * HID + c];
            float w3 = W[(k + 3) * HID + c];
            #pragma unroll
            for (int ri = 0; ri < RMAX; ++ri) {
                int r = rg + 2 * ri;
                if (r < NPG) {
                    float4 mv = *(const float4*)&m[r][k];
                    acc[ri] = fmaf(mv.x, w0, fmaf(mv.y, w1, fmaf(mv.z, w2, fmaf(mv.w, w3, acc[ri]))));
                }
            }
        }
        #pragma unroll
        for (int ri = 0; ri < RMAX; ++ri) {
            int r = rg + 2 * ri;
            if (r < NPG) {
                float v = fmaf(acc[ri] + bc, scale, shift);  // BN(conv_out)
                v = fmaxf(v, 0.0f);                           // ReLU
                h[r][c] = v + h[r][c];                        // residual
            }
        }
        __syncthreads();
    }

    // ---- theta = relu(h @ physW1 + b1) @ physW2 + b2  (per node) ----
    {
        int j = tid & 15;
        int ig = tid >> 4;  // 0..15
        float w2j = physW2[j];
        float b1j = physb1[j];
        for (int i = ig; i < NPG; i += 16) {
            float s = b1j;
            for (int k = 0; k < HID; k += 4) {
                float4 hv = *(const float4*)&h[i][k];
                s = fmaf(hv.x, physW1[(k + 0) * 16 + j],
                    fmaf(hv.y, physW1[(k + 1) * 16 + j],
                    fmaf(hv.z, physW1[(k + 2) * 16 + j],
                    fmaf(hv.w, physW1[(k + 3) * 16 + j], s))));
            }
            float part = fmaxf(s, 0.0f) * w2j;
            #pragma unroll
            for (int o = 8; o; o >>= 1)
                part += __shfl_down(part, o, 16);
            if (j == 0) theta[i] = part + physb2[0];
        }
    }

    // ---- P = h @ mlpW1[0:128]  -> m ----
    {
        float acc[RMAX];
        #pragma unroll
        for (int ri = 0; ri < RMAX; ++ri) acc[ri] = 0.0f;
        for (int k = 0; k < HID; k += 4) {
            float w0 = mlpW1[(k + 0) * HID + c];
            float w1 = mlpW1[(k + 1) * HID + c];
            float w2 = mlpW1[(k + 2) * HID + c];
            float w3 = mlpW1[(k + 3) * HID + c];
            #pragma unroll
            for (int ri = 0; ri < RMAX; ++ri) {
                int r = rg + 2 * ri;
                if (r < NPG) {
                    float4 hv = *(const float4*)&h[r][k];
                    acc[ri] = fmaf(hv.x, w0, fmaf(hv.y, w1, fmaf(hv.z, w2, fmaf(hv.w, w3, acc[ri]))));
                }
            }
        }
        #pragma unroll
        for (int ri = 0; ri < RMAX; ++ri) {
            int r = rg + 2 * ri;
            if (r < NPG) m[r][c] = acc[ri];
        }
    }

    // ---- Q = h @ mlpW1[128:256] -> h (in place; reads all done before writes) ----
    {
        const float* __restrict__ Wq = mlpW1 + 128 * HID;
        float acc[RMAX];
        #pragma unroll
        for (int ri = 0; ri < RMAX; ++ri) acc[ri] = 0.0f;
        for (int k = 0; k < HID; k += 4) {
            float w0 = Wq[(k + 0) * HID + c];
            float w1 = Wq[(k + 1) * HID + c];
            float w2 = Wq[(k + 2) * HID + c];
            float w3 = Wq[(k + 3) * HID + c];
            #pragma unroll
            for (int ri = 0; ri < RMAX; ++ri) {
                int r = rg + 2 * ri;
                if (r < NPG) {
                    float4 hv = *(const float4*)&h[r][k];
                    acc[ri] = fmaf(hv.x, w0, fmaf(hv.y, w1, fmaf(hv.z, w2, fmaf(hv.w, w3, acc[ri]))));
                }
            }
        }
        __syncthreads();   // ALL reads of h (theta/P/Q) complete before overwrite
        #pragma unroll
        for (int ri = 0; ri < RMAX; ++ri) {
            int r = rg + 2 * ri;
            if (r < NPG) h[r][c] = acc[ri];
        }
    }
    __syncthreads();   // theta, m(P), h(Q) all visible

    // ---- combine: out[e] = relu(P[u]+Q[v]+dth*w256+b1) @ mlpW2 + b2 ----
    {
        float w256 = mlpW1[256 * HID + c];
        float b1c = mlpb1[c];
        float w2c = mlpW2[c];
        for (int e = rg; e < NB; e += 2) {
            int u = branch_u[e];
            int v = branch_v[e];
            float dth = theta[u] - theta[v];
            float val = m[u][c] + h[v][c] + fmaf(dth, w256, b1c);
            val = fmaxf(val, 0.0f) * w2c;
            #pragma unroll
            for (int o = 32; o; o >>= 1)
                val += __shfl_down(val, o, 64);
            if ((tid & 63) == 0)
                atomicAdd(&red[e], val);
        }
    }
    __syncthreads();
    if (tid < NB) out[g * NB + tid] = red[tid] + mlpb2[0];
}

extern "C" void kernel_launch(void* const* d_in, const int* in_sizes, int n_in,
                              void* d_out, int out_size, void* d_ws, size_t ws_size,
                              hipStream_t stream) {
    const float* x          = (const float*)d_in[0];
    const int*   edge_index = (const int*)d_in[1];
    const int*   branch_u   = (const int*)d_in[2];
    const int*   branch_v   = (const int*)d_in[3];
    const float* Wp         = (const float*)d_in[4];
    const float* bp         = (const float*)d_in[5];
    const float* convW      = (const float*)d_in[6];
    const float* convb      = (const float*)d_in[7];
    const float* bn_gamma   = (const float*)d_in[8];
    const float* bn_beta    = (const float*)d_in[9];
    const float* bn_mean    = (const float*)d_in[10];
    const float* bn_var     = (const float*)d_in[11];
    const float* physW1     = (const float*)d_in[12];
    const float* physb1     = (const float*)d_in[13];
    const float* physW2     = (const float*)d_in[14];
    const float* physb2     = (const float*)d_in[15];
    const float* mlpW1      = (const float*)d_in[16];
    const float* mlpb1      = (const float*)d_in[17];
    const float* mlpW2      = (const float*)d_in[18];
    const float* mlpb2      = (const float*)d_in[19];
    float* out = (float*)d_out;

    pinn_fused<<<NG, 256, 0, stream>>>(
        x, edge_index, branch_u, branch_v, Wp, bp, convW, convb,
        bn_gamma, bn_beta, bn_mean, bn_var, physW1, physb1, physW2, physb2,
        mlpW1, mlpb1, mlpW2, mlpb2, out);
}

// Round 2
// 1466.262 us; speedup vs baseline: 2.5530x; 2.5530x over previous
//
#include <hip/hip_runtime.h>

#define NPG 57       // nodes per graph
#define NEPG 160     // edges per graph
#define NB 80        // branches per graph
#define HID 128
#define NG 4096      // graphs
#define NL 5

typedef __attribute__((ext_vector_type(8))) short bf16x8;
typedef __attribute__((ext_vector_type(4))) float f32x4;

__device__ __forceinline__ short f2bf(float f) {
    unsigned u = __builtin_bit_cast(unsigned, f);
    u += 0x7fff + ((u >> 16) & 1);          // round-to-nearest-even
    return (short)(u >> 16);
}
__device__ __forceinline__ float bf2f(short s) {
    unsigned u = ((unsigned)(unsigned short)s) << 16;
    return __builtin_bit_cast(float, u);
}

// ---- weight prep: transpose + hi/lo bf16 split into ws ----
// ws layout: short wb[7][2][128][128]  (mat, hi/lo, n, k)   = 458752 B
__global__ void prep_weights(const float* __restrict__ convW,
                             const float* __restrict__ mlpW1,
                             short* __restrict__ wb) {
    int id = blockIdx.x * 256 + threadIdx.x;
    if (id >= 7 * 16384) return;
    int mat = id >> 14;
    int rem = id & 16383;
    int n = rem >> 7;
    int k = rem & 127;
    float w;
    if (mat < 5)       w = convW[mat * 16384 + k * 128 + n];
    else if (mat == 5) w = mlpW1[k * 128 + n];            // P part
    else               w = mlpW1[(128 + k) * 128 + n];    // Q part
    short hi = f2bf(w);
    short lo = f2bf(w - bf2f(hi));
    wb[(mat * 2 + 0) * 16384 + n * 128 + k] = hi;
    wb[(mat * 2 + 1) * 16384 + n * 128 + k] = lo;
}

// ---- per-wave 64x128 tile matmul via bf16x3 MFMA ----
// A: [64][128] fp32 in LDS (optionally 16B-XOR-swizzled); W from ws (hi,lo)
template<int SWZ>
__device__ __forceinline__ void mm_tile(f32x4 acc[8], const float (*A)[HID],
                                        const short* __restrict__ whi,
                                        const short* __restrict__ wlo,
                                        int lane, int wv) {
    const int ln15 = lane & 15;
    const int kb = (lane >> 4) << 3;          // 0,8,16,24
    const int row = 16 * wv + ln15;
    const int sw = SWZ ? ((row & 7) << 2) : 0;
    bf16x8 ahi[4], alo[4];
    const float* rp = A[row];
#pragma unroll
    for (int ks = 0; ks < 4; ++ks) {
        int k0 = 32 * ks + kb;
        float4 q0 = *(const float4*)&rp[(k0) ^ sw];
        float4 q1 = *(const float4*)&rp[(k0 + 4) ^ sw];
        float f[8] = {q0.x, q0.y, q0.z, q0.w, q1.x, q1.y, q1.z, q1.w};
        bf16x8 h8, l8;
#pragma unroll
        for (int j = 0; j < 8; ++j) {
            short hj = f2bf(f[j]);
            h8[j] = hj;
            l8[j] = f2bf(f[j] - bf2f(hj));
        }
        ahi[ks] = h8;
        alo[ks] = l8;
    }
#pragma unroll
    for (int ct = 0; ct < 8; ++ct) {
        f32x4 a = {0.f, 0.f, 0.f, 0.f};
        const short* bh = whi + (16 * ct + ln15) * HID + kb;
        const short* bl = wlo + (16 * ct + ln15) * HID + kb;
#pragma unroll
        for (int ks = 0; ks < 4; ++ks) {
            bf16x8 bhi = *(const bf16x8*)(bh + 32 * ks);
            bf16x8 blo = *(const bf16x8*)(bl + 32 * ks);
            a = __builtin_amdgcn_mfma_f32_16x16x32_bf16(ahi[ks], bhi, a, 0, 0, 0);
            a = __builtin_amdgcn_mfma_f32_16x16x32_bf16(ahi[ks], blo, a, 0, 0, 0);
            a = __builtin_amdgcn_mfma_f32_16x16x32_bf16(alo[ks], bhi, a, 0, 0, 0);
        }
        acc[ct] = a;
    }
}

__global__ __launch_bounds__(256, 2) void pinn_fused(
    const float* __restrict__ x, const int* __restrict__ edge_index,
    const int* __restrict__ branch_u, const int* __restrict__ branch_v,
    const float* __restrict__ Wp, const float* __restrict__ bp,
    const float* __restrict__ convb,
    const float* __restrict__ bn_gamma, const float* __restrict__ bn_beta,
    const float* __restrict__ bn_mean, const float* __restrict__ bn_var,
    const float* __restrict__ physW1, const float* __restrict__ physb1,
    const float* __restrict__ physW2, const float* __restrict__ physb2,
    const float* __restrict__ mlpW1, const float* __restrict__ mlpb1,
    const float* __restrict__ mlpW2, const float* __restrict__ mlpb2,
    const short* __restrict__ wb, float* __restrict__ out) {
    __shared__ float h[64][HID];     // fp32 features (+ zero pad rows 57-63)
    __shared__ float mf[64][HID];    // aggregated / P buffer (16B-XOR swizzled)
    __shared__ float dinv[NPG];
    __shared__ int   deg[NPG];
    __shared__ int   rowptr[NPG + 1];
    __shared__ int   cursor[NPG];
    __shared__ short esrc[NEPG], edst[NEPG];
    __shared__ int2  csre[NEPG];     // x=src, y=bitcast(norm)
    __shared__ float theta[NPG];
    __shared__ float red[NB];

    const int g = blockIdx.x;
    const int tid = threadIdx.x;
    const int lane = tid & 63;
    const int wv = tid >> 6;       // wave 0..3 -> row tile
    const int c = tid & 127;
    const int rg = tid >> 7;       // 0/1

    // zero pad rows + init
    for (int i = tid; i < 7 * HID; i += 256) {
        h[57 + (i >> 7)][i & 127] = 0.f;
        mf[57 + (i >> 7)][i & 127] = 0.f;
    }
    if (tid < NPG) deg[tid] = 0;
    if (tid < NB) red[tid] = 0.f;
    __syncthreads();

    // edges -> local indices, in-degree
    if (tid < NEPG) {
        int gs = edge_index[g * NEPG + tid];
        int gd = edge_index[NG * NEPG + g * NEPG + tid];
        short ls = (short)(gs - g * NPG);
        short ld = (short)(gd - g * NPG);
        esrc[tid] = ls;
        edst[tid] = ld;
        atomicAdd(&deg[ld], 1);
    }
    __syncthreads();
    if (tid < NPG) dinv[tid] = rsqrtf(1.0f + (float)deg[tid]);
    if (tid == 0) {
        int run = 0;
        for (int i = 0; i < NPG; ++i) { rowptr[i] = run; run += deg[i]; }
        rowptr[NPG] = run;
    }
    __syncthreads();
    if (tid < NPG) cursor[tid] = rowptr[tid];
    __syncthreads();
    if (tid < NEPG) {
        int s = esrc[tid], d = edst[tid];
        int pos = atomicAdd(&cursor[d], 1);
        float nw = dinv[s] * dinv[d];
        csre[pos] = make_int2(s, __builtin_bit_cast(int, nw));
    }

    // projection: h = x @ Wp + bp
    {
        float w0 = Wp[c], w1 = Wp[HID + c], w2 = Wp[2 * HID + c], w3 = Wp[3 * HID + c];
        float bb = bp[c];
        for (int r = rg; r < NPG; r += 2) {
            float4 xv = ((const float4*)x)[g * NPG + r];
            h[r][c] = fmaf(xv.x, w0, fmaf(xv.y, w1, fmaf(xv.z, w2, fmaf(xv.w, w3, bb))));
        }
    }
    __syncthreads();

    // ---- 5 GCN layers ----
    for (int l = 0; l < NL; ++l) {
        // CSR gather aggregation -> mf (swizzled)
        for (int r = rg; r < NPG; r += 2) {
            float acc = dinv[r] * dinv[r] * h[r][c];
            int e1 = rowptr[r + 1];
            for (int e = rowptr[r]; e < e1; ++e) {
                int2 ce = csre[e];
                acc = fmaf(__builtin_bit_cast(float, ce.y), h[ce.x][c], acc);
            }
            mf[r][c ^ ((r & 7) << 2)] = acc;
        }
        __syncthreads();

        // conv matmul + BN + ReLU + residual
        f32x4 acc[8];
        mm_tile<1>(acc, mf, wb + (2 * l) * 16384, wb + (2 * l + 1) * 16384, lane, wv);
        const int ln15 = lane & 15;
        const int r0 = 16 * wv + 4 * (lane >> 4);
#pragma unroll
        for (int ct = 0; ct < 8; ++ct) {
            int ch = 16 * ct + ln15;
            float sc = bn_gamma[l * HID + ch] * rsqrtf(bn_var[l * HID + ch] + 1e-5f);
            float sh = bn_beta[l * HID + ch] - bn_mean[l * HID + ch] * sc;
            float bc = convb[l * HID + ch];
#pragma unroll
            for (int q = 0; q < 4; ++q) {
                int rr = r0 + q;
                if (rr < NPG) {
                    float v = fmaf(acc[ct][q] + bc, sc, sh);
                    h[rr][ch] = fmaxf(v, 0.f) + h[rr][ch];
                }
            }
        }
        __syncthreads();
    }

    // ---- theta (VALU, small) ----
    {
        int j = tid & 15, ig = tid >> 4;
        float w2j = physW2[j], b1j = physb1[j];
        for (int i = ig; i < NPG; i += 16) {
            float s = b1j;
            for (int k = 0; k < HID; k += 4) {
                float4 hv = *(const float4*)&h[i][k];
                s = fmaf(hv.x, physW1[(k + 0) * 16 + j],
                    fmaf(hv.y, physW1[(k + 1) * 16 + j],
                    fmaf(hv.z, physW1[(k + 2) * 16 + j],
                    fmaf(hv.w, physW1[(k + 3) * 16 + j], s))));
            }
            float part = fmaxf(s, 0.f) * w2j;
#pragma unroll
            for (int o = 8; o; o >>= 1) part += __shfl_down(part, o, 16);
            if (j == 0) theta[i] = part + physb2[0];
        }
    }

    // ---- P = h @ mlpW1[0:128] -> mf (swizzled) ----
    {
        f32x4 acc[8];
        mm_tile<0>(acc, h, wb + 10 * 16384, wb + 11 * 16384, lane, wv);
        const int ln15 = lane & 15;
        const int r0 = 16 * wv + 4 * (lane >> 4);
#pragma unroll
        for (int ct = 0; ct < 8; ++ct) {
            int ch = 16 * ct + ln15;
#pragma unroll
            for (int q = 0; q < 4; ++q) {
                int rr = r0 + q;
                if (rr < NPG) mf[rr][ch ^ ((rr & 7) << 2)] = acc[ct][q];
            }
        }
    }
    // ---- Q = h @ mlpW1[128:256] -> h (in place after full barrier) ----
    {
        f32x4 acc[8];
        mm_tile<0>(acc, h, wb + 12 * 16384, wb + 13 * 16384, lane, wv);
        __syncthreads();   // all reads of h (theta/P/Q) complete
        const int ln15 = lane & 15;
        const int r0 = 16 * wv + 4 * (lane >> 4);
#pragma unroll
        for (int ct = 0; ct < 8; ++ct) {
            int ch = 16 * ct + ln15;
#pragma unroll
            for (int q = 0; q < 4; ++q) {
                int rr = r0 + q;
                if (rr < NPG) h[rr][ch] = acc[ct][q];
            }
        }
    }
    __syncthreads();

    // ---- combine per branch ----
    {
        float w256 = mlpW1[256 * HID + c];
        float b1c = mlpb1[c];
        float w2c = mlpW2[c];
        for (int e = rg; e < NB; e += 2) {
            int u = branch_u[e], v = branch_v[e];
            float dth = theta[u] - theta[v];
            float val = mf[u][c ^ ((u & 7) << 2)] + h[v][c] + fmaf(dth, w256, b1c);
            val = fmaxf(val, 0.f) * w2c;
#pragma unroll
            for (int o = 32; o; o >>= 1) val += __shfl_down(val, o, 64);
            if (lane == 0) atomicAdd(&red[e], val);
        }
    }
    __syncthreads();
    if (tid < NB) out[g * NB + tid] = red[tid] + mlpb2[0];
}

extern "C" void kernel_launch(void* const* d_in, const int* in_sizes, int n_in,
                              void* d_out, int out_size, void* d_ws, size_t ws_size,
                              hipStream_t stream) {
    const float* x          = (const float*)d_in[0];
    const int*   edge_index = (const int*)d_in[1];
    const int*   branch_u   = (const int*)d_in[2];
    const int*   branch_v   = (const int*)d_in[3];
    const float* Wp         = (const float*)d_in[4];
    const float* bp         = (const float*)d_in[5];
    const float* convW      = (const float*)d_in[6];
    const float* convb      = (const float*)d_in[7];
    const float* bn_gamma   = (const float*)d_in[8];
    const float* bn_beta    = (const float*)d_in[9];
    const float* bn_mean    = (const float*)d_in[10];
    const float* bn_var     = (const float*)d_in[11];
    const float* physW1     = (const float*)d_in[12];
    const float* physb1     = (const float*)d_in[13];
    const float* physW2     = (const float*)d_in[14];
    const float* physb2     = (const float*)d_in[15];
    const float* mlpW1      = (const float*)d_in[16];
    const float* mlpb1      = (const float*)d_in[17];
    const float* mlpW2      = (const float*)d_in[18];
    const float* mlpb2      = (const float*)d_in[19];
    float* out = (float*)d_out;
    short* wb = (short*)d_ws;   // 458752 B needed

    prep_weights<<<448, 256, 0, stream>>>(convW, mlpW1, wb);
    pinn_fused<<<NG, 256, 0, stream>>>(
        x, edge_index, branch_u, branch_v, Wp, bp, convb,
        bn_gamma, bn_beta, bn_mean, bn_var, physW1, physb1, physW2, physb2,
        mlpW1, mlpb1, mlpW2, mlpb2, wb, out);
}